// Round 5
// baseline (1598.848 us; speedup 1.0000x reference)
//
#include <hip/hip_runtime.h>

// ============================================================
// ModifiedLSTM: B=64 T=2048 I=128 H=256 L=2 C=64
// Only the post-last-reset segment of each row matters (~3.3k of 131k steps).
// Recurrence: 4 independent WGs (1 per 16-row cluster), 1024 thr (16 waves,
// 4/SIMD), i8 weights in VGPRs (mfma_i32_16x16x64_i8), h via LDS+barrier.
// R5: 16 waves to fill issue slots; f32 xh0 (precision + zero conv VALU);
// simplified xg layout (unit*4+gate).
// ============================================================

#define CAPROWS 6144

// ws layout (bytes), total 36 MiB
#define OFF_CTRL   0u           // int[256]: t0[64], len[64]@64, off[64]@128, total@192
#define OFF_ROWMAP 1024u        // int[CAPROWS]
#define OFF_H1L    65536u       // float[64][256]
#define OFF_XH0    (2u<<20)     // float[CAPROWS][256] layer-0 h compact (6 MiB)
#define OFF_XIN1   (8u<<20)     // ushort[CAPROWS][256] (3 MiB)
#define OFF_XG0    (12u<<20)    // ushort[CAPROWS][1024] (12 MiB) pos=unit*4+gate
#define OFF_XG1    (24u<<20)    // ushort[CAPROWS][1024] (12 MiB)

typedef short sh8 __attribute__((ext_vector_type(8)));
typedef float fl4 __attribute__((ext_vector_type(4)));
typedef int i4 __attribute__((ext_vector_type(4)));

__device__ __forceinline__ unsigned short f2bf(float f) {
  union { float f; unsigned u; } v; v.f = f;
  unsigned r = v.u + 0x7fffu + ((v.u >> 16) & 1u);
  return (unsigned short)(r >> 16);
}
__device__ __forceinline__ float bf2f(unsigned short h) {
  union { unsigned u; float f; } v; v.u = ((unsigned)h) << 16; return v.f;
}
__device__ __forceinline__ float u2f(unsigned u) {
  union { unsigned u; float f; } v; v.u = u; return v.f;
}
__device__ __forceinline__ float sigm(float x) {
  return __builtin_amdgcn_rcpf(1.f + __builtin_amdgcn_exp2f(-1.4426950408889634f * x));
}
__device__ __forceinline__ float tanh_f(float x) {
  return 1.f - 2.f * __builtin_amdgcn_rcpf(1.f + __builtin_amdgcn_exp2f(2.8853900817779268f * x));
}

// -------- K1: per-row last-zero scan --------
__global__ __launch_bounds__(256) void scan_kernel(const float* __restrict__ mask,
                                                   int* __restrict__ ctrl) {
  int b = blockIdx.x;
  int best = -1;
  for (int t = threadIdx.x; t < 2048; t += 256)
    if (mask[b * 2048 + t] == 0.0f) best = max(best, t);
  __shared__ int red[256];
  red[threadIdx.x] = best;
  __syncthreads();
  for (int o = 128; o; o >>= 1) {
    if (threadIdx.x < o) red[threadIdx.x] = max(red[threadIdx.x], red[threadIdx.x + o]);
    __syncthreads();
  }
  if (threadIdx.x == 0) {
    ctrl[b] = red[0];
    ctrl[64 + b] = 2047 - red[0];
  }
}

// -------- K2: prefix offsets, rowmap, zero h1last --------
__global__ __launch_bounds__(256) void setup_kernel(int* __restrict__ ctrl,
                                                    int* __restrict__ rowmap,
                                                    unsigned int* __restrict__ h1l_u32) {
  __shared__ int off_s[64];
  if (threadIdx.x == 0) {
    int acc = 0;
    for (int b = 0; b < 64; b++) { off_s[b] = acc; ctrl[128 + b] = acc; acc += ctrl[64 + b]; }
    ctrl[192] = min(acc, CAPROWS);
  }
  __syncthreads();
  for (int b = 0; b < 64; b++) {
    int len = ctrl[64 + b], off = off_s[b];
    for (int s = threadIdx.x; s < len; s += 256) {
      int rc = off + s;
      if (rc < CAPROWS) rowmap[rc] = (b << 16) | s;
    }
  }
  for (int i = threadIdx.x; i < 16384; i += 256) h1l_u32[i] = 0u;
}

// -------- gate preactivation GEMM (pos = unit*4 + gate) --------
__global__ __launch_bounds__(256) void gx_kernel(const float* __restrict__ seq,
                                                 const unsigned short* __restrict__ xin1,
                                                 const float* __restrict__ Wih,
                                                 const float* __restrict__ bih,
                                                 const float* __restrict__ bhh,
                                                 const int* __restrict__ ctrl,
                                                 const int* __restrict__ rowmap,
                                                 unsigned short* __restrict__ xg_out,
                                                 const int K, const int layer) {
  int total = ctrl[192];
  int r0 = blockIdx.x * 8;
  if (r0 >= total) return;
  __shared__ float A[8][260];
  for (int idx = threadIdx.x; idx < 8 * K; idx += 256) {
    int r = idx / K, k = idx - r * K;
    int rc = r0 + r;
    float v = 0.f;
    if (rc < total) {
      if (layer == 0) {
        int bm = rowmap[rc];
        int b = bm >> 16, s = bm & 0xFFFF;
        int t = ctrl[b] + 1 + s;
        v = seq[((size_t)b * 2048 + t) * 128 + k];
      } else {
        v = bf2f(xin1[(size_t)rc * 256 + k]);
      }
    }
    A[r][k] = v;
  }
  __syncthreads();
  int u = threadIdx.x;  // unit 0..255
  float acc[4][8];
  #pragma unroll
  for (int n = 0; n < 4; n++)
    #pragma unroll
    for (int r = 0; r < 8; r++) acc[n][r] = 0.f;
  const float* wr0 = Wih + (size_t)(u + 0) * K;
  const float* wr1 = Wih + (size_t)(u + 256) * K;
  const float* wr2 = Wih + (size_t)(u + 512) * K;
  const float* wr3 = Wih + (size_t)(u + 768) * K;
  for (int k4 = 0; k4 < K; k4 += 4) {
    float4 av[8];
    #pragma unroll
    for (int r = 0; r < 8; r++) av[r] = *(const float4*)&A[r][k4];
    float4 wv0 = *(const float4*)(wr0 + k4);
    float4 wv1 = *(const float4*)(wr1 + k4);
    float4 wv2 = *(const float4*)(wr2 + k4);
    float4 wv3 = *(const float4*)(wr3 + k4);
    #pragma unroll
    for (int r = 0; r < 8; r++) {
      acc[0][r] += wv0.x * av[r].x + wv0.y * av[r].y + wv0.z * av[r].z + wv0.w * av[r].w;
      acc[1][r] += wv1.x * av[r].x + wv1.y * av[r].y + wv1.z * av[r].z + wv1.w * av[r].w;
      acc[2][r] += wv2.x * av[r].x + wv2.y * av[r].y + wv2.z * av[r].z + wv2.w * av[r].w;
      acc[3][r] += wv3.x * av[r].x + wv3.y * av[r].y + wv3.z * av[r].z + wv3.w * av[r].w;
    }
  }
  float bsum[4];
  #pragma unroll
  for (int n = 0; n < 4; n++) bsum[n] = bih[n * 256 + u] + bhh[n * 256 + u];
  const int pos = u * 4;  // gates consecutive per unit
  #pragma unroll
  for (int r = 0; r < 8; r++) {
    int rc = r0 + r;
    if (rc < total) {
      unsigned long long pk =
          (unsigned long long)f2bf(acc[0][r] + bsum[0]) |
          ((unsigned long long)f2bf(acc[1][r] + bsum[1]) << 16) |
          ((unsigned long long)f2bf(acc[2][r] + bsum[2]) << 32) |
          ((unsigned long long)f2bf(acc[3][r] + bsum[3]) << 48);
      *(unsigned long long*)&xg_out[(size_t)rc * 1024 + pos] = pk;
    }
  }
}

// -------- recurrence: 1 WG (1024 thr, 16 waves) per 16-row cluster --------
__global__ __launch_bounds__(1024, 1) void rec_kernel(const float* __restrict__ Whh,
                                                      const unsigned short* __restrict__ xg,
                                                      const int* __restrict__ ctrl,
                                                      float* __restrict__ xh0,     // f32 h out (layer0)
                                                      float* __restrict__ h1last,  // layer1 out
                                                      const int layer) {
  const int tid = threadIdx.x;
  const int lane = tid & 63;
  const int w = tid >> 6;        // wave 0..15, owns units [16w, 16w+16)
  const int n = lane & 15;
  const int q = lane >> 4;
  const int cidx = blockIdx.x;   // cluster: batch rows [16c, 16c+16)
  const int u = w * 16 + n;

  __shared__ char h8[2][16 * 272];  // [parity][row][swizzled 16B unit-blocks]

  // ---- prologue: load + per-row-scale quantize Whh into B fragments ----
  i4 bfr[4][4];
  float fscale[4];
  #pragma unroll
  for (int g = 0; g < 4; g++) {
    const float* wp = Whh + (size_t)(g * 256 + u) * 256 + q * 16;
    float mx = 0.f;
    #pragma unroll
    for (int kk = 0; kk < 4; kk++) {
      #pragma unroll
      for (int j = 0; j < 4; j++) {
        float4 x = *(const float4*)(wp + kk * 64 + j * 4);
        mx = fmaxf(mx, fmaxf(fmaxf(fabsf(x.x), fabsf(x.y)), fmaxf(fabsf(x.z), fabsf(x.w))));
      }
    }
    mx = fmaxf(mx, __shfl_xor(mx, 16, 64));
    mx = fmaxf(mx, __shfl_xor(mx, 32, 64));
    const float sinv = mx > 0.f ? 127.f / mx : 0.f;
    fscale[g] = mx * (1.f / 16129.f);
    #pragma unroll
    for (int kk = 0; kk < 4; kk++) {
      int pw[4];
      #pragma unroll
      for (int j = 0; j < 4; j++) {
        float4 x = *(const float4*)(wp + kk * 64 + j * 4);
        int b0 = (int)rintf(x.x * sinv), b1 = (int)rintf(x.y * sinv);
        int b2 = (int)rintf(x.z * sinv), b3 = (int)rintf(x.w * sinv);
        pw[j] = (b0 & 255) | ((b1 & 255) << 8) | ((b2 & 255) << 16) | ((b3 & 255) << 24);
      }
      bfr[g][kk] = (i4){pw[0], pw[1], pw[2], pw[3]};
    }
  }

  // zero h_0 (parity 0 buffer: 4352 B)
  for (int i = tid; i < 1088; i += 1024) ((int*)h8[0])[i] = 0;

  int lenr[4], offr[4], lenm1[4];
  #pragma unroll
  for (int r = 0; r < 4; r++) {
    const int b = cidx * 16 + q * 4 + r;
    lenr[r] = ctrl[64 + b];
    offr[r] = ctrl[128 + b];
    lenm1[r] = max(lenr[r] - 1, 0);
  }
  int S = max(max(lenr[0], lenr[1]), max(lenr[2], lenr[3]));
  #pragma unroll
  for (int d = 1; d < 64; d <<= 1) S = max(S, __shfl_xor(S, d, 64));

  // A-frag swizzled read offsets: row m=n, phys block (4kk+q-2n)&15
  int aoff[4];
  #pragma unroll
  for (int kk = 0; kk < 4; kk++)
    aoff[kk] = n * 272 + (((4 * kk + q - 2 * n) & 15) << 4);
  // h write offsets: row=q*4+r, unit block=w, phys=(w-2*row)&15
  int woff[4];
  #pragma unroll
  for (int r = 0; r < 4; r++) {
    int row = q * 4 + r;
    woff[r] = row * 272 + (((w - 2 * row) & 15) << 4) + n;
  }

  // incremental pointers: xg (frozen at last valid row), xh0, h1last
  const unsigned long long* xp[4];
  float* hp[4];
  #pragma unroll
  for (int r = 0; r < 4; r++) {
    xp[r] = (const unsigned long long*)(xg + (size_t)min(offr[r], CAPROWS - 1) * 1024 + u * 4);
    hp[r] = (layer == 0 ? xh0 + (size_t)offr[r] * 256
                        : h1last + (size_t)(cidx * 16 + q * 4 + r) * 256) + u;
  }

  float cst[4] = {0.f, 0.f, 0.f, 0.f};

  __syncthreads();

  for (int s = 0; s < S; s++) {
    const int par = s & 1;
    // xg loads issued early, consumed after the MFMAs (~600 cy of cover)
    unsigned long long xgr[4];
    #pragma unroll
    for (int r = 0; r < 4; r++) {
      xgr[r] = *xp[r];
      if (s < lenm1[r]) xp[r] += 256;  // +2048 B = one xg row
    }
    // MFMAs: 4 gate tiles x 4 k-chunks (A frag consumed per chunk)
    i4 acc[4];
    #pragma unroll
    for (int g = 0; g < 4; g++) acc[g] = (i4){0, 0, 0, 0};
    #pragma unroll
    for (int kk = 0; kk < 4; kk++) {
      i4 af = *(const i4*)&h8[par][aoff[kk]];
      #pragma unroll
      for (int g = 0; g < 4; g++)
        acc[g] = __builtin_amdgcn_mfma_i32_16x16x64_i8(af, bfr[g][kk], acc[g], 0, 0, 0);
    }

    // gates + state update (LDS publish pre-barrier; global stores post-barrier)
    float hnv[4];
    #pragma unroll
    for (int r = 0; r < 4; r++) {
      const unsigned w0 = (unsigned)xgr[r];
      const unsigned w1 = (unsigned)(xgr[r] >> 32);
      const float gi = fmaf((float)acc[0][r], fscale[0], u2f(w0 << 16));
      const float gf = fmaf((float)acc[1][r], fscale[1], u2f(w0 & 0xFFFF0000u));
      const float gg = fmaf((float)acc[2][r], fscale[2], u2f(w1 << 16));
      const float go = fmaf((float)acc[3][r], fscale[3], u2f(w1 & 0xFFFF0000u));
      const float iv = sigm(gi);
      const float fv = sigm(gf);
      const float gv = tanh_f(gg);
      const float ov = sigm(go);
      const float cn = fv * cst[r] + iv * gv;
      const float hn = ov * tanh_f(cn);
      cst[r] = cn;
      h8[par ^ 1][woff[r]] = (char)(int)rintf(hn * 127.f);
      hnv[r] = hn;
    }
    __syncthreads();

    // global stores off the barrier path
    if (layer == 0) {
      #pragma unroll
      for (int r = 0; r < 4; r++) {
        if (s < lenr[r]) hp[r][0] = hnv[r];
        hp[r] += 256;
      }
    } else {
      #pragma unroll
      for (int r = 0; r < 4; r++) {
        if (s == lenr[r] - 1) hp[r][0] = hnv[r];
      }
    }
  }
}

// -------- LN + ReLU over compact layer-0 h rows (f32 input) --------
__global__ __launch_bounds__(64) void ln_relu_kernel(const float* __restrict__ xin,
                                                     const float* __restrict__ g,
                                                     const float* __restrict__ bb,
                                                     unsigned short* __restrict__ xout,
                                                     const int* __restrict__ ctrl) {
  int total = ctrl[192];
  int t = threadIdx.x;
  for (int row = blockIdx.x; row < total; row += (int)gridDim.x) {
    float4 vv = *(const float4*)&xin[(size_t)row * 256 + t * 4];
    float v[4] = {vv.x, vv.y, vv.z, vv.w};
    float s1 = v[0] + v[1] + v[2] + v[3];
    float s2 = v[0]*v[0] + v[1]*v[1] + v[2]*v[2] + v[3]*v[3];
    #pragma unroll
    for (int d = 1; d < 64; d <<= 1) { s1 += __shfl_xor(s1, d, 64); s2 += __shfl_xor(s2, d, 64); }
    float mu = s1 * (1.f / 256.f);
    float var = s2 * (1.f / 256.f) - mu * mu;
    float rs = rsqrtf(var + 1e-5f);
    #pragma unroll
    for (int i = 0; i < 4; i++) {
      int j = t * 4 + i;
      float y = (v[i] - mu) * rs * g[j] + bb[j];
      xout[(size_t)row * 256 + j] = f2bf(fmaxf(y, 0.f));
    }
  }
}

// -------- final: LN + ReLU on h1last, then FC --------
__global__ __launch_bounds__(64) void fc_kernel(const float* __restrict__ h1last,
                                                const float* __restrict__ g,
                                                const float* __restrict__ bb,
                                                const float* __restrict__ fcW,
                                                const float* __restrict__ fcb,
                                                float* __restrict__ out) {
  int b = blockIdx.x, t = threadIdx.x;
  float v[4];
  #pragma unroll
  for (int i = 0; i < 4; i++) v[i] = h1last[b * 256 + t * 4 + i];
  float s1 = v[0] + v[1] + v[2] + v[3];
  float s2 = v[0]*v[0] + v[1]*v[1] + v[2]*v[2] + v[3]*v[3];
  #pragma unroll
  for (int d = 1; d < 64; d <<= 1) { s1 += __shfl_xor(s1, d, 64); s2 += __shfl_xor(s2, d, 64); }
  float mu = s1 * (1.f / 256.f);
  float var = s2 * (1.f / 256.f) - mu * mu;
  float rs = rsqrtf(var + 1e-5f);
  __shared__ float x[256];
  #pragma unroll
  for (int i = 0; i < 4; i++) {
    int j = t * 4 + i;
    float y = (v[i] - mu) * rs * g[j] + bb[j];
    x[j] = fmaxf(y, 0.f);
  }
  float acc = fcb[t];
  const float* wr = fcW + t * 256;
  for (int k = 0; k < 256; k += 4) {
    float4 wv = *(const float4*)(wr + k);
    acc += wv.x * x[k] + wv.y * x[k + 1] + wv.z * x[k + 2] + wv.w * x[k + 3];
  }
  out[b * 64 + t] = acc;
}

extern "C" void kernel_launch(void* const* d_in, const int* in_sizes, int n_in,
                              void* d_out, int out_size, void* d_ws, size_t ws_size,
                              hipStream_t stream) {
  const float* seq  = (const float*)d_in[0];
  const float* mask = (const float*)d_in[1];
  const float* Wih0 = (const float*)d_in[2];
  const float* Whh0 = (const float*)d_in[3];
  const float* bih0 = (const float*)d_in[4];
  const float* bhh0 = (const float*)d_in[5];
  const float* lng0 = (const float*)d_in[6];
  const float* lnb0 = (const float*)d_in[7];
  const float* Wih1 = (const float*)d_in[8];
  const float* Whh1 = (const float*)d_in[9];
  const float* bih1 = (const float*)d_in[10];
  const float* bhh1 = (const float*)d_in[11];
  const float* lng1 = (const float*)d_in[12];
  const float* lnb1 = (const float*)d_in[13];
  const float* fcW  = (const float*)d_in[14];
  const float* fcb  = (const float*)d_in[15];

  char* ws = (char*)d_ws;
  int* ctrl = (int*)(ws + OFF_CTRL);
  int* rowmap = (int*)(ws + OFF_ROWMAP);
  float* h1last = (float*)(ws + OFF_H1L);
  float* xh0 = (float*)(ws + OFF_XH0);
  unsigned short* xin1 = (unsigned short*)(ws + OFF_XIN1);
  unsigned short* xg0 = (unsigned short*)(ws + OFF_XG0);
  unsigned short* xg1 = (unsigned short*)(ws + OFF_XG1);

  scan_kernel<<<64, 256, 0, stream>>>(mask, ctrl);
  setup_kernel<<<1, 256, 0, stream>>>(ctrl, rowmap, (unsigned int*)h1last);
  gx_kernel<<<CAPROWS / 8, 256, 0, stream>>>(seq, nullptr, Wih0, bih0, bhh0,
                                             ctrl, rowmap, xg0, 128, 0);
  rec_kernel<<<4, 1024, 0, stream>>>(Whh0, xg0, ctrl, xh0, nullptr, 0);
  ln_relu_kernel<<<2048, 64, 0, stream>>>(xh0, lng0, lnb0, xin1, ctrl);
  gx_kernel<<<CAPROWS / 8, 256, 0, stream>>>(nullptr, xin1, Wih1, bih1, bhh1,
                                             ctrl, rowmap, xg1, 256, 1);
  rec_kernel<<<4, 1024, 0, stream>>>(Whh1, xg1, ctrl, nullptr, h1last, 1);
  fc_kernel<<<64, 64, 0, stream>>>(h1last, lng1, lnb1, fcW, fcb, (float*)d_out);
}

// Round 6
// 818.082 us; speedup vs baseline: 1.9544x; 1.9544x over previous
//
#include <hip/hip_runtime.h>

// ============================================================
// ModifiedLSTM: B=64 T=2048 I=128 H=256 L=2 C=64
// Only the post-last-reset segment of each row matters (~3.3k of 131k steps).
// R6: rows are independent -> 16 WGs x 4 batch rows (16 CUs), rows at
// M-positions {0,4,8,12} so C/D reg 0 of each quad is a valid row (100% lane
// utilization in gate math, 4x less VALU per CU). i8 weights in VGPRs/AGPRs
// (mfma_i32_16x16x64_i8), h exchanged via LDS + 1 barrier/step.
// ============================================================

#define CAPROWS 6144

// ws layout (bytes), total 36 MiB
#define OFF_CTRL   0u           // int[256]: t0[64], len[64]@64, off[64]@128, total@192
#define OFF_ROWMAP 1024u        // int[CAPROWS]
#define OFF_H1L    65536u       // float[64][256]
#define OFF_XH0    (2u<<20)     // float[CAPROWS][256] layer-0 h compact (6 MiB)
#define OFF_XIN1   (8u<<20)     // ushort[CAPROWS][256] (3 MiB)
#define OFF_XG0    (12u<<20)    // ushort[CAPROWS][1024] (12 MiB) pos=unit*4+gate
#define OFF_XG1    (24u<<20)    // ushort[CAPROWS][1024] (12 MiB)

typedef short sh8 __attribute__((ext_vector_type(8)));
typedef float fl4 __attribute__((ext_vector_type(4)));
typedef int i4 __attribute__((ext_vector_type(4)));

__device__ __forceinline__ unsigned short f2bf(float f) {
  union { float f; unsigned u; } v; v.f = f;
  unsigned r = v.u + 0x7fffu + ((v.u >> 16) & 1u);
  return (unsigned short)(r >> 16);
}
__device__ __forceinline__ float bf2f(unsigned short h) {
  union { unsigned u; float f; } v; v.u = ((unsigned)h) << 16; return v.f;
}
__device__ __forceinline__ float u2f(unsigned u) {
  union { unsigned u; float f; } v; v.u = u; return v.f;
}
__device__ __forceinline__ float sigm(float x) {
  return __builtin_amdgcn_rcpf(1.f + __builtin_amdgcn_exp2f(-1.4426950408889634f * x));
}
__device__ __forceinline__ float tanh_f(float x) {
  return 1.f - 2.f * __builtin_amdgcn_rcpf(1.f + __builtin_amdgcn_exp2f(2.8853900817779268f * x));
}

// -------- K1: per-row last-zero scan --------
__global__ __launch_bounds__(256) void scan_kernel(const float* __restrict__ mask,
                                                   int* __restrict__ ctrl) {
  int b = blockIdx.x;
  int best = -1;
  for (int t = threadIdx.x; t < 2048; t += 256)
    if (mask[b * 2048 + t] == 0.0f) best = max(best, t);
  __shared__ int red[256];
  red[threadIdx.x] = best;
  __syncthreads();
  for (int o = 128; o; o >>= 1) {
    if (threadIdx.x < o) red[threadIdx.x] = max(red[threadIdx.x], red[threadIdx.x + o]);
    __syncthreads();
  }
  if (threadIdx.x == 0) {
    ctrl[b] = red[0];
    ctrl[64 + b] = 2047 - red[0];
  }
}

// -------- K2: prefix offsets, rowmap, zero h1last --------
__global__ __launch_bounds__(256) void setup_kernel(int* __restrict__ ctrl,
                                                    int* __restrict__ rowmap,
                                                    unsigned int* __restrict__ h1l_u32) {
  __shared__ int off_s[64];
  if (threadIdx.x == 0) {
    int acc = 0;
    for (int b = 0; b < 64; b++) { off_s[b] = acc; ctrl[128 + b] = acc; acc += ctrl[64 + b]; }
    ctrl[192] = min(acc, CAPROWS);
  }
  __syncthreads();
  for (int b = 0; b < 64; b++) {
    int len = ctrl[64 + b], off = off_s[b];
    for (int s = threadIdx.x; s < len; s += 256) {
      int rc = off + s;
      if (rc < CAPROWS) rowmap[rc] = (b << 16) | s;
    }
  }
  for (int i = threadIdx.x; i < 16384; i += 256) h1l_u32[i] = 0u;
}

// -------- gate preactivation GEMM (pos = unit*4 + gate) --------
__global__ __launch_bounds__(256) void gx_kernel(const float* __restrict__ seq,
                                                 const unsigned short* __restrict__ xin1,
                                                 const float* __restrict__ Wih,
                                                 const float* __restrict__ bih,
                                                 const float* __restrict__ bhh,
                                                 const int* __restrict__ ctrl,
                                                 const int* __restrict__ rowmap,
                                                 unsigned short* __restrict__ xg_out,
                                                 const int K, const int layer) {
  int total = ctrl[192];
  int r0 = blockIdx.x * 8;
  if (r0 >= total) return;
  __shared__ float A[8][260];
  for (int idx = threadIdx.x; idx < 8 * K; idx += 256) {
    int r = idx / K, k = idx - r * K;
    int rc = r0 + r;
    float v = 0.f;
    if (rc < total) {
      if (layer == 0) {
        int bm = rowmap[rc];
        int b = bm >> 16, s = bm & 0xFFFF;
        int t = ctrl[b] + 1 + s;
        v = seq[((size_t)b * 2048 + t) * 128 + k];
      } else {
        v = bf2f(xin1[(size_t)rc * 256 + k]);
      }
    }
    A[r][k] = v;
  }
  __syncthreads();
  int u = threadIdx.x;  // unit 0..255
  float acc[4][8];
  #pragma unroll
  for (int n = 0; n < 4; n++)
    #pragma unroll
    for (int r = 0; r < 8; r++) acc[n][r] = 0.f;
  const float* wr0 = Wih + (size_t)(u + 0) * K;
  const float* wr1 = Wih + (size_t)(u + 256) * K;
  const float* wr2 = Wih + (size_t)(u + 512) * K;
  const float* wr3 = Wih + (size_t)(u + 768) * K;
  for (int k4 = 0; k4 < K; k4 += 4) {
    float4 av[8];
    #pragma unroll
    for (int r = 0; r < 8; r++) av[r] = *(const float4*)&A[r][k4];
    float4 wv0 = *(const float4*)(wr0 + k4);
    float4 wv1 = *(const float4*)(wr1 + k4);
    float4 wv2 = *(const float4*)(wr2 + k4);
    float4 wv3 = *(const float4*)(wr3 + k4);
    #pragma unroll
    for (int r = 0; r < 8; r++) {
      acc[0][r] += wv0.x * av[r].x + wv0.y * av[r].y + wv0.z * av[r].z + wv0.w * av[r].w;
      acc[1][r] += wv1.x * av[r].x + wv1.y * av[r].y + wv1.z * av[r].z + wv1.w * av[r].w;
      acc[2][r] += wv2.x * av[r].x + wv2.y * av[r].y + wv2.z * av[r].z + wv2.w * av[r].w;
      acc[3][r] += wv3.x * av[r].x + wv3.y * av[r].y + wv3.z * av[r].z + wv3.w * av[r].w;
    }
  }
  float bsum[4];
  #pragma unroll
  for (int n = 0; n < 4; n++) bsum[n] = bih[n * 256 + u] + bhh[n * 256 + u];
  const int pos = u * 4;  // gates consecutive per unit
  #pragma unroll
  for (int r = 0; r < 8; r++) {
    int rc = r0 + r;
    if (rc < total) {
      unsigned long long pk =
          (unsigned long long)f2bf(acc[0][r] + bsum[0]) |
          ((unsigned long long)f2bf(acc[1][r] + bsum[1]) << 16) |
          ((unsigned long long)f2bf(acc[2][r] + bsum[2]) << 32) |
          ((unsigned long long)f2bf(acc[3][r] + bsum[3]) << 48);
      *(unsigned long long*)&xg_out[(size_t)rc * 1024 + pos] = pk;
    }
  }
}

// -------- recurrence: 16 WGs (512 thr, 8 waves), 4 batch rows per WG --------
// batch row j of this WG lives at MFMA M-position 4j -> C/D quad j, reg 0.
__global__ __launch_bounds__(512, 2) void rec_kernel(const float* __restrict__ Whh,
                                                     const unsigned short* __restrict__ xg,
                                                     const int* __restrict__ ctrl,
                                                     float* __restrict__ xh0,     // f32 h out (layer0)
                                                     float* __restrict__ h1last,  // layer1 out
                                                     const int layer) {
  const int tid = threadIdx.x;
  const int lane = tid & 63;
  const int w = tid >> 6;        // wave 0..7, owns units [32w, 32w+32)
  const int n = lane & 15;
  const int q = lane >> 4;       // = batch row index within WG (for C/D, xg, gates)
  const int wg = blockIdx.x;     // batch rows [4*wg, 4*wg+4)

  __shared__ char h8[2][16 * 272];  // [parity][16 M-rows][swizzled 16B blocks]

  // ---- prologue: quantize Whh into B fragments (8 tiles: a in {0,1}, g in {0..3}) ----
  // tile t=a*4+g: B row n -> Whh row R = g*256 + 32w + 16a + n; k = kk*64 + q*16 + j
  i4 bfr[8][4];
  float fscale[8];
  #pragma unroll
  for (int t = 0; t < 8; t++) {
    const int a = t >> 2, g = t & 3;
    const float* wp = Whh + (size_t)(g * 256 + 32 * w + 16 * a + n) * 256 + q * 16;
    float mx = 0.f;
    #pragma unroll
    for (int kk = 0; kk < 4; kk++) {
      #pragma unroll
      for (int j = 0; j < 4; j++) {
        float4 x = *(const float4*)(wp + kk * 64 + j * 4);
        mx = fmaxf(mx, fmaxf(fmaxf(fabsf(x.x), fabsf(x.y)), fmaxf(fabsf(x.z), fabsf(x.w))));
      }
    }
    mx = fmaxf(mx, __shfl_xor(mx, 16, 64));
    mx = fmaxf(mx, __shfl_xor(mx, 32, 64));
    const float sinv = mx > 0.f ? 127.f / mx : 0.f;
    fscale[t] = mx * (1.f / 16129.f);
    #pragma unroll
    for (int kk = 0; kk < 4; kk++) {
      int pw[4];
      #pragma unroll
      for (int j = 0; j < 4; j++) {
        float4 x = *(const float4*)(wp + kk * 64 + j * 4);
        int b0 = (int)rintf(x.x * sinv), b1 = (int)rintf(x.y * sinv);
        int b2 = (int)rintf(x.z * sinv), b3 = (int)rintf(x.w * sinv);
        pw[j] = (b0 & 255) | ((b1 & 255) << 8) | ((b2 & 255) << 16) | ((b3 & 255) << 24);
      }
      bfr[t][kk] = (i4){pw[0], pw[1], pw[2], pw[3]};
    }
  }

  // zero BOTH parities (non-4j M-rows must stay zero forever)
  for (int i = tid; i < 2176; i += 512) ((int*)h8)[i] = 0;

  // per-lane row control: my row = q
  const int b = wg * 4 + q;
  const int len = ctrl[64 + b];
  const int off = ctrl[128 + b];
  const int lenm1 = max(len - 1, 0);
  int S = len;
  #pragma unroll
  for (int d = 1; d < 64; d <<= 1) S = max(S, __shfl_xor(S, d, 64));

  // A-frag swizzled read offsets: row m=lane&15, logical block B=4kk+q -> phys (B-2m)&15
  int aoff[4];
  #pragma unroll
  for (int kk = 0; kk < 4; kk++)
    aoff[kk] = n * 272 + (((4 * kk + q - 2 * n) & 15) << 4);
  // h write offsets: M-row 4q, unit block cb=2w+a, phys=(cb-8q)&15, byte n
  int woff[2];
  #pragma unroll
  for (int a = 0; a < 2; a++)
    woff[a] = (4 * q) * 272 + (((2 * w + a - 8 * q) & 15) << 4) + n;

  // incremental pointers (frozen at last valid row)
  const unsigned short* xp =
      xg + (size_t)min(off, CAPROWS - 1) * 1024 + (32 * w + n) * 4;
  float* hp = (layer == 0 ? xh0 + (size_t)off * 256
                          : h1last + (size_t)b * 256) + 32 * w + n;

  float cst[2] = {0.f, 0.f};

  __syncthreads();

  // prime xg for s=0 (two 8B loads: units 32w+n and 32w+16+n)
  unsigned long long xl0 = *(const unsigned long long*)xp;
  unsigned long long xl1 = *(const unsigned long long*)(xp + 64);

  for (int s = 0; s < S; s++) {
    const int par = s & 1;
    // MFMAs: 8 tiles x 4 k-chunks
    i4 acc[8];
    #pragma unroll
    for (int t = 0; t < 8; t++) acc[t] = (i4){0, 0, 0, 0};
    #pragma unroll
    for (int kk = 0; kk < 4; kk++) {
      i4 af = *(const i4*)&h8[par][aoff[kk]];
      #pragma unroll
      for (int t = 0; t < 8; t++)
        acc[t] = __builtin_amdgcn_mfma_i32_16x16x64_i8(af, bfr[t][kk], acc[t], 0, 0, 0);
    }

    // prefetch xg for s+1 under the gate math
    if (s < lenm1) xp += 1024;  // +2048 B = one xg row
    unsigned long long nl0 = *(const unsigned long long*)xp;
    unsigned long long nl1 = *(const unsigned long long*)(xp + 64);

    // gates (reg 0 of each tile = my row q), 2 units per lane
    float hnv[2];
    #pragma unroll
    for (int a = 0; a < 2; a++) {
      const unsigned long long xv = a ? xl1 : xl0;
      const unsigned w0 = (unsigned)xv;
      const unsigned w1 = (unsigned)(xv >> 32);
      const float gi = fmaf((float)acc[a * 4 + 0][0], fscale[a * 4 + 0], u2f(w0 << 16));
      const float gf = fmaf((float)acc[a * 4 + 1][0], fscale[a * 4 + 1], u2f(w0 & 0xFFFF0000u));
      const float gg = fmaf((float)acc[a * 4 + 2][0], fscale[a * 4 + 2], u2f(w1 << 16));
      const float go = fmaf((float)acc[a * 4 + 3][0], fscale[a * 4 + 3], u2f(w1 & 0xFFFF0000u));
      const float iv = sigm(gi);
      const float fv = sigm(gf);
      const float gv = tanh_f(gg);
      const float ov = sigm(go);
      const float cn = fv * cst[a] + iv * gv;
      const float hn = ov * tanh_f(cn);
      cst[a] = cn;
      h8[par ^ 1][woff[a]] = (char)(int)rintf(hn * 127.f);
      hnv[a] = hn;
    }
    __syncthreads();

    // global stores off the barrier path
    if (layer == 0) {
      if (s < len) { hp[0] = hnv[0]; hp[16] = hnv[1]; }
      hp += 256;
    } else {
      if (s == len - 1) { hp[0] = hnv[0]; hp[16] = hnv[1]; }
    }
    xl0 = nl0;
    xl1 = nl1;
  }
}

// -------- LN + ReLU over compact layer-0 h rows (f32 input) --------
__global__ __launch_bounds__(64) void ln_relu_kernel(const float* __restrict__ xin,
                                                     const float* __restrict__ g,
                                                     const float* __restrict__ bb,
                                                     unsigned short* __restrict__ xout,
                                                     const int* __restrict__ ctrl) {
  int total = ctrl[192];
  int t = threadIdx.x;
  for (int row = blockIdx.x; row < total; row += (int)gridDim.x) {
    float4 vv = *(const float4*)&xin[(size_t)row * 256 + t * 4];
    float v[4] = {vv.x, vv.y, vv.z, vv.w};
    float s1 = v[0] + v[1] + v[2] + v[3];
    float s2 = v[0]*v[0] + v[1]*v[1] + v[2]*v[2] + v[3]*v[3];
    #pragma unroll
    for (int d = 1; d < 64; d <<= 1) { s1 += __shfl_xor(s1, d, 64); s2 += __shfl_xor(s2, d, 64); }
    float mu = s1 * (1.f / 256.f);
    float var = s2 * (1.f / 256.f) - mu * mu;
    float rs = rsqrtf(var + 1e-5f);
    #pragma unroll
    for (int i = 0; i < 4; i++) {
      int j = t * 4 + i;
      float y = (v[i] - mu) * rs * g[j] + bb[j];
      xout[(size_t)row * 256 + j] = f2bf(fmaxf(y, 0.f));
    }
  }
}

// -------- final: LN + ReLU on h1last, then FC --------
__global__ __launch_bounds__(64) void fc_kernel(const float* __restrict__ h1last,
                                                const float* __restrict__ g,
                                                const float* __restrict__ bb,
                                                const float* __restrict__ fcW,
                                                const float* __restrict__ fcb,
                                                float* __restrict__ out) {
  int b = blockIdx.x, t = threadIdx.x;
  float v[4];
  #pragma unroll
  for (int i = 0; i < 4; i++) v[i] = h1last[b * 256 + t * 4 + i];
  float s1 = v[0] + v[1] + v[2] + v[3];
  float s2 = v[0]*v[0] + v[1]*v[1] + v[2]*v[2] + v[3]*v[3];
  #pragma unroll
  for (int d = 1; d < 64; d <<= 1) { s1 += __shfl_xor(s1, d, 64); s2 += __shfl_xor(s2, d, 64); }
  float mu = s1 * (1.f / 256.f);
  float var = s2 * (1.f / 256.f) - mu * mu;
  float rs = rsqrtf(var + 1e-5f);
  __shared__ float x[256];
  #pragma unroll
  for (int i = 0; i < 4; i++) {
    int j = t * 4 + i;
    float y = (v[i] - mu) * rs * g[j] + bb[j];
    x[j] = fmaxf(y, 0.f);
  }
  float acc = fcb[t];
  const float* wr = fcW + t * 256;
  for (int k = 0; k < 256; k += 4) {
    float4 wv = *(const float4*)(wr + k);
    acc += wv.x * x[k] + wv.y * x[k + 1] + wv.z * x[k + 2] + wv.w * x[k + 3];
  }
  out[b * 64 + t] = acc;
}

extern "C" void kernel_launch(void* const* d_in, const int* in_sizes, int n_in,
                              void* d_out, int out_size, void* d_ws, size_t ws_size,
                              hipStream_t stream) {
  const float* seq  = (const float*)d_in[0];
  const float* mask = (const float*)d_in[1];
  const float* Wih0 = (const float*)d_in[2];
  const float* Whh0 = (const float*)d_in[3];
  const float* bih0 = (const float*)d_in[4];
  const float* bhh0 = (const float*)d_in[5];
  const float* lng0 = (const float*)d_in[6];
  const float* lnb0 = (const float*)d_in[7];
  const float* Wih1 = (const float*)d_in[8];
  const float* Whh1 = (const float*)d_in[9];
  const float* bih1 = (const float*)d_in[10];
  const float* bhh1 = (const float*)d_in[11];
  const float* lng1 = (const float*)d_in[12];
  const float* lnb1 = (const float*)d_in[13];
  const float* fcW  = (const float*)d_in[14];
  const float* fcb  = (const float*)d_in[15];

  char* ws = (char*)d_ws;
  int* ctrl = (int*)(ws + OFF_CTRL);
  int* rowmap = (int*)(ws + OFF_ROWMAP);
  float* h1last = (float*)(ws + OFF_H1L);
  float* xh0 = (float*)(ws + OFF_XH0);
  unsigned short* xin1 = (unsigned short*)(ws + OFF_XIN1);
  unsigned short* xg0 = (unsigned short*)(ws + OFF_XG0);
  unsigned short* xg1 = (unsigned short*)(ws + OFF_XG1);

  scan_kernel<<<64, 256, 0, stream>>>(mask, ctrl);
  setup_kernel<<<1, 256, 0, stream>>>(ctrl, rowmap, (unsigned int*)h1last);
  gx_kernel<<<CAPROWS / 8, 256, 0, stream>>>(seq, nullptr, Wih0, bih0, bhh0,
                                             ctrl, rowmap, xg0, 128, 0);
  rec_kernel<<<16, 512, 0, stream>>>(Whh0, xg0, ctrl, xh0, nullptr, 0);
  ln_relu_kernel<<<2048, 64, 0, stream>>>(xh0, lng0, lnb0, xin1, ctrl);
  gx_kernel<<<CAPROWS / 8, 256, 0, stream>>>(nullptr, xin1, Wih1, bih1, bhh1,
                                             ctrl, rowmap, xg1, 256, 1);
  rec_kernel<<<16, 512, 0, stream>>>(Whh1, xg1, ctrl, nullptr, h1last, 1);
  fc_kernel<<<64, 64, 0, stream>>>(h1last, lng1, lnb1, fcW, fcb, (float*)d_out);
}